// Round 4
// baseline (1097.227 us; speedup 1.0000x reference)
//
#include <hip/hip_runtime.h>
#include <hip/hip_bf16.h>
#include <hip/hip_cooperative_groups.h>

namespace cg = cooperative_groups;

// Problem constants:
#define BATCH 8
#define NQ    75
#define WAY   5
#define PN    121
#define DIM   640
#define SSZ   605        // shot * patch_num
#define TOPK  3

#define KCH 10           // DIM / 64
#define NCH 5            // 640 / 128

// Workspace: bf16, MFMA-tile-packed, XOR-swizzled (chunk_phys = chunk_log ^ (row&7)).
//   Q: [bq=600][kc=10] tiles of [row=128][chunk=8]x16B  (6000 tiles)
//   S: [bw=40][nc=5][kc=10] tiles                        (2000 tiles)
#define NQTILES 6000
#define NSTILES 2000
#define WS_NEED   ((size_t)(NQTILES + NSTILES) * 16384)   // 131,072,000 B

typedef __attribute__((ext_vector_type(8))) short   short8;
typedef __attribute__((ext_vector_type(8))) __bf16  bf16x8;
typedef __attribute__((ext_vector_type(4))) float   f32x4;

__device__ inline unsigned short f2bf(float f) {
  unsigned u = __builtin_bit_cast(unsigned, f);
  return (unsigned short)((u + 0x7fffu + ((u >> 16) & 1u)) >> 16);
}
__device__ inline unsigned pk2(float lo, float hi) {
  return (unsigned)f2bf(lo) | ((unsigned)f2bf(hi) << 16);
}

// branchless insert into sorted-descending triple: 1 max + 2 med3
__device__ inline void ins3(float &a, float &b, float &c, float v) {
  float na  = fmaxf(a, v);
  float nb  = __builtin_amdgcn_fmed3f(v, a, b);
  float nc2 = __builtin_amdgcn_fmed3f(v, b, c);
  a = na; b = nb; c = nc2;
}

// async 16B global->LDS (DMA; LDS dest = wave-uniform base + lane*16)
__device__ inline void async_copy16(const void* g, void* l) {
  __builtin_amdgcn_global_load_lds(
      (const __attribute__((address_space(1))) unsigned int*)g,
      (__attribute__((address_space(3))) unsigned int*)l, 16, 0, 0);
}

// ---------------- pack unit: one 32-row quarter of one tile frame ------------
// 3200 quarter-units total: Q = 600 slabs x 4 quarters (per batch: 300),
// S = 200 frames x 4 quarters (per batch: 100) -> 400 units per batch.
// Same f2bf/pk2/XOR-swizzle/zero-pad as the verified round-3 cvt_pack.
__device__ __forceinline__ void pack_unit(int unit_b, int j,
                                          const float* __restrict__ qf,
                                          const float* __restrict__ sf,
                                          uint4* __restrict__ wq,
                                          uint4* __restrict__ wsp) {
  const float* src;      // frame base (row 0 of the 128-row tile frame)
  uint4* dstbase;        // first kc tile of this frame
  int nrows, rowbase;
  if (j < 300) {
    const int q = j >> 2;
    rowbase = (j & 3) << 5;
    const int slab = unit_b * NQ + q;
    src = qf + (size_t)slab * PN * DIM;
    dstbase = wq + (size_t)slab * KCH * 1024;
    nrows = PN;
  } else {
    const int l = j - 300;
    rowbase = (l & 3) << 5;
    const int fi = l >> 2;          // 0..24 = w*5 + nc
    const int nc = fi % NCH;
    const int w  = fi / NCH;
    const int bw = unit_b * WAY + w;
    const int uv = bw * NCH + nc;
    src = sf + ((size_t)bw * SSZ + nc * 128) * DIM;
    dstbase = wsp + (size_t)uv * KCH * 1024;
    nrows = SSZ - nc * 128; if (nrows > 128) nrows = 128;
  }
  // 32 rows x 80 segments (8 floats in, 16B out each) = 2560 segs, 10 iters.
  #pragma unroll 2
  for (int i = 0; i < 10; ++i) {
    const int L    = i * 256 + threadIdx.x;   // 0..2559
    const int rowl = L / 80;
    const int s    = L - rowl * 80;           // 0..79: global 8-float segment
    const int row  = rowbase + rowl;          // tile-local row 0..127
    const int kc   = s >> 3;
    const int c    = s & 7;                   // logical chunk within kc window
    const int p    = c ^ (row & 7);           // physical chunk slot (swizzle)
    uint4 o = make_uint4(0u, 0u, 0u, 0u);
    if (row < nrows) {
      const float* g = src + (size_t)row * DIM + s * 8;
      float4 v0 = reinterpret_cast<const float4*>(g)[0];
      float4 v1 = reinterpret_cast<const float4*>(g)[1];
      o.x = pk2(v0.x, v0.y); o.y = pk2(v0.z, v0.w);
      o.z = pk2(v1.x, v1.y); o.w = pk2(v1.z, v1.w);
    }
    dstbase[(size_t)kc * 1024 + row * 8 + p] = o;
  }
}

// ---------------- main block body (round-0 structure, verbatim) --------------
// Measured 341-348us standalone, MfmaUtil ~41, 0 bank conflicts, 3 blocks/CU.
// sbid -> bid XCD swizzle: XCD k owns batch k (per-XCD working set: 5 S slabs
// = 4 MB = one L2, plus one 160 KB Q slab shared by 5 w-blocks).
__device__ __forceinline__ void main_block(int sbid,
                                           const char* __restrict__ wq,
                                           const char* __restrict__ wsp,
                                           float* __restrict__ out,
                                           char* Qs, char* Ss, float* red) {
  const int bid  = (sbid & 7) * (NQ * WAY) + (sbid >> 3);

  const int w   = bid % WAY;
  const int bq  = bid / WAY;            // b*NQ + q
  const int b   = bid / (WAY * NQ);

  const char* Qtiles = wq  + (size_t)bq * KCH * 16384;
  const char* Stiles = wsp + (size_t)(b * WAY + w) * NCH * KCH * 16384;

  const int tid  = threadIdx.x;
  const int lane = tid & 63;
  const int wv   = tid >> 6;
  const int l15  = lane & 15;
  const int quad = lane >> 4;
  const int mrow0 = (wv >> 1) * 64;     // quadrant row base
  const int ncol0 = (wv & 1) * 64;      // quadrant col base

  // swizzled chunk byte offsets (XOR distributes over the <<4)
  const int sw16 = (l15 & 7) * 16;
  const int cp0  = (quad * 16) ^ sw16;        // kk = 0
  const int cp1  = ((4 + quad) * 16) ^ sw16;  // kk = 1

  const char* qb = Qs + (mrow0 + l15) * 128;
  const char* sb = Ss + (ncol0 + l15) * 128;

  // per-lane running top-3 for 16 owned rows: row = mrow0 + mt*16 + quad*4 + r
  float t3a[4][4], t3b[4][4], t3c[4][4];
  #pragma unroll
  for (int mt = 0; mt < 4; ++mt)
    #pragma unroll
    for (int r = 0; r < 4; ++r) {
      t3a[mt][r] = -3.0e38f; t3b[mt][r] = -3.0e38f; t3c[mt][r] = -3.0e38f;
    }

  for (int nc = 0; nc < NCH; ++nc) {
    f32x4 acc[4][4];
    #pragma unroll
    for (int mt = 0; mt < 4; ++mt)
      #pragma unroll
      for (int nt = 0; nt < 4; ++nt)
        acc[mt][nt] = (f32x4){0.f, 0.f, 0.f, 0.f};

    #pragma unroll 1
    for (int kc = 0; kc < KCH; ++kc) {
      __syncthreads();   // previous iteration's readers done
      {
        const char* qsl = Qtiles + (size_t)kc * 16384;
        const char* ssl = Stiles + ((size_t)nc * KCH + kc) * 16384;
        #pragma unroll
        for (int i = 0; i < 4; ++i) {
          int ch = wv * 4 + i;
          async_copy16(qsl + ch * 1024 + lane * 16, Qs + ch * 1024);
          async_copy16(ssl + ch * 1024 + lane * 16, Ss + ch * 1024);
        }
      }
      __syncthreads();   // drains vmcnt (DMA complete)

      #pragma unroll
      for (int kk = 0; kk < 2; ++kk) {
        const int cp = kk ? cp1 : cp0;
        short8 a[4], bf[4];
        #pragma unroll
        for (int mt = 0; mt < 4; ++mt)
          a[mt] = *reinterpret_cast<const short8*>(qb + mt * 2048 + cp);
        #pragma unroll
        for (int nt = 0; nt < 4; ++nt)
          bf[nt] = *reinterpret_cast<const short8*>(sb + nt * 2048 + cp);
        #pragma unroll
        for (int mt = 0; mt < 4; ++mt)
          #pragma unroll
          for (int nt = 0; nt < 4; ++nt)
            acc[mt][nt] = __builtin_amdgcn_mfma_f32_16x16x32_bf16(
                __builtin_bit_cast(bf16x8, a[mt]),
                __builtin_bit_cast(bf16x8, bf[nt]), acc[mt][nt], 0, 0, 0);
      }
    }

    // fold this 128-col chunk into register top-3 (mask pad cols >= 605)
    #pragma unroll
    for (int nt = 0; nt < 4; ++nt) {
      int col = nc * 128 + ncol0 + nt * 16 + l15;
      bool valid = col < SSZ;
      #pragma unroll
      for (int mt = 0; mt < 4; ++mt)
        #pragma unroll
        for (int r = 0; r < 4; ++r) {
          float v = valid ? acc[mt][nt][r] : -3.0e38f;
          ins3(t3a[mt][r], t3b[mt][r], t3c[mt][r], v);
        }
    }
  }

  // butterfly-merge top-3 across the 16 l15 lanes (same rows, different cols)
  #pragma unroll
  for (int m = 1; m < 16; m <<= 1) {
    #pragma unroll
    for (int mt = 0; mt < 4; ++mt)
      #pragma unroll
      for (int r = 0; r < 4; ++r) {
        float o0 = __shfl_xor(t3a[mt][r], m);
        float o1 = __shfl_xor(t3b[mt][r], m);
        float o2 = __shfl_xor(t3c[mt][r], m);
        ins3(t3a[mt][r], t3b[mt][r], t3c[mt][r], o0);
        ins3(t3a[mt][r], t3b[mt][r], t3c[mt][r], o1);
        ins3(t3a[mt][r], t3b[mt][r], t3c[mt][r], o2);
      }
  }

  // cross-half merge via LDS scratch (reuse Qs): waves 1,3 publish; 0,2 merge
  float* tb = reinterpret_cast<float*>(Qs);   // [128][3]
  __syncthreads();
  if ((wv & 1) == 1 && l15 == 0) {
    #pragma unroll
    for (int mt = 0; mt < 4; ++mt)
      #pragma unroll
      for (int r = 0; r < 4; ++r) {
        int row = mrow0 + mt * 16 + quad * 4 + r;
        tb[row * 3 + 0] = t3a[mt][r];
        tb[row * 3 + 1] = t3b[mt][r];
        tb[row * 3 + 2] = t3c[mt][r];
      }
  }
  __syncthreads();
  if ((wv & 1) == 0 && l15 == 0) {
    #pragma unroll
    for (int mt = 0; mt < 4; ++mt)
      #pragma unroll
      for (int r = 0; r < 4; ++r) {
        int row = mrow0 + mt * 16 + quad * 4 + r;
        ins3(t3a[mt][r], t3b[mt][r], t3c[mt][r], tb[row * 3 + 0]);
        ins3(t3a[mt][r], t3b[mt][r], t3c[mt][r], tb[row * 3 + 1]);
        ins3(t3a[mt][r], t3b[mt][r], t3c[mt][r], tb[row * 3 + 2]);
      }
  }
  __syncthreads();
  if ((wv & 1) == 0 && l15 == 0) {
    #pragma unroll
    for (int mt = 0; mt < 4; ++mt)
      #pragma unroll
      for (int r = 0; r < 4; ++r) {
        int row = mrow0 + mt * 16 + quad * 4 + r;
        tb[row * 3 + 0] = t3a[mt][r];
        tb[row * 3 + 1] = t3b[mt][r];
        tb[row * 3 + 2] = t3c[mt][r];
      }
  }
  __syncthreads();

  // mean over valid rows (<121) and k
  float s = 0.f;
  for (int i = tid; i < PN * TOPK; i += 256) s += tb[i];
  #pragma unroll
  for (int off = 32; off > 0; off >>= 1) s += __shfl_down(s, off);
  if (lane == 0) red[wv] = s;
  __syncthreads();
  if (tid == 0)
    out[bid] = (red[0] + red[1] + red[2] + red[3]) * (1.0f / (PN * TOPK));
}

// ---------------- fused cooperative kernel ----------------
// NEW this round: one dispatch = pack phase + grid.sync + main phase.
// Purpose: (1) attribution — the single dispatch's counters finally expose the
// ~280us gap between total and lpc_main; (2) XCD-local producer/consumer:
// persistent block g packs batch g&7, which is exactly the batch its
// main-phase sbids (g mod 8 preserved since nblk%8==0) consume — pack output
// stays dirty in the consumer XCD's own L2. Correctness does NOT depend on
// the block->XCD mapping: device-scope __threadfence() + grid.sync() replace
// the kernel-boundary acquire/release of the 2-kernel version.
__global__ __launch_bounds__(256, 3) void lpc_fused(
    const float* __restrict__ qf, const float* __restrict__ sf,
    uint4* __restrict__ wq, uint4* __restrict__ wsp,
    float* __restrict__ out, int nblk)
{
  __shared__ char Qs[16384];
  __shared__ char Ss[16384];
  __shared__ float red[4];

  const int g  = blockIdx.x;
  const int bb = g & 7;                      // batch this block packs/consumes
  for (int j = g >> 3; j < 400; j += (nblk >> 3))
    pack_unit(bb, j, qf, sf, wq, wsp);

  __threadfence();                           // release: ws writes device-visible
  cg::this_grid().sync();
  __threadfence();                           // acquire: drop stale ws lines

  for (int sbid = g; sbid < BATCH * NQ * WAY; sbid += nblk)
    main_block(sbid, (const char*)wq, (const char*)wsp, out, Qs, Ss, red);
}

// ---------------- standalone kernels (fallback if cooperative fails) --------
__global__ __launch_bounds__(256) void cvt_pack(const float* __restrict__ qf,
                                                const float* __restrict__ sf,
                                                uint4* __restrict__ wq,
                                                uint4* __restrict__ wsp) {
  // 1600 half-frame units (round-3 verified version, 64 rows each) == two
  // quarter-units back to back.
  const int blk = blockIdx.x;
  int b, j0;
  if (blk < 1200) { const int slab = blk >> 1; b = slab / NQ;
    j0 = (slab - b * NQ) * 4 + (blk & 1) * 2; }
  else { const int u = blk - 1200; const int uv = u >> 1;   // bw*5+nc
    const int bw = uv / NCH; b = bw / WAY;
    const int fi = (bw - b * WAY) * NCH + (uv % NCH);
    j0 = 300 + fi * 4 + (u & 1) * 2; }
  pack_unit(b, j0, qf, sf, wq, wsp);
  pack_unit(b, j0 + 1, qf, sf, wq, wsp);
}

__global__ __launch_bounds__(256, 3) void lpc_main(
    const char* __restrict__ wq, const char* __restrict__ wsp,
    float* __restrict__ out)
{
  __shared__ char Qs[16384];
  __shared__ char Ss[16384];
  __shared__ float red[4];
  main_block(blockIdx.x, wq, wsp, out, Qs, Ss, red);
}

// ---------------- fallback (direct from fp32, only if ws too small) ---------
__global__ __launch_bounds__(256) void lpc_fallback(
    const float* __restrict__ qf, const float* __restrict__ sf,
    float* __restrict__ out)
{
  __shared__ short Qst[128][72];
  __shared__ short Sst[64][72];
  __shared__ float Cs[128][67];
  __shared__ float top3[128][TOPK];
  __shared__ float red[4];

  const int bid = blockIdx.x;
  const int w   = bid % WAY;
  const int qi  = (bid / WAY) % NQ;
  const int b   = bid / (WAY * NQ);
  const float* Qb = qf + ((size_t)(b * NQ + qi)) * PN * DIM;
  const float* Sb = sf + ((size_t)(b * WAY + w)) * SSZ * DIM;
  const int tid  = threadIdx.x;
  const int lane = tid & 63;
  const int wv   = tid >> 6;
  const int l15  = lane & 15;
  const int quad = lane >> 4;

  if (tid < 128) { top3[tid][0] = -3.0e38f; top3[tid][1] = -3.0e38f; top3[tid][2] = -3.0e38f; }
  f32x4 acc[2][4];
  for (int nc = 0; nc < 10; ++nc) {
    const int sbase = nc * 64;
    int vn = SSZ - sbase; if (vn > 64) vn = 64;
    #pragma unroll
    for (int mt = 0; mt < 2; ++mt)
      #pragma unroll
      for (int nt = 0; nt < 4; ++nt) acc[mt][nt] = (f32x4){0.f,0.f,0.f,0.f};
    for (int kc = 0; kc < KCH; ++kc) {
      const int kbase = kc * 64;
      __syncthreads();
      #pragma unroll
      for (int i = 0; i < 8; ++i) {
        int lin = i * 256 + tid; int row = lin >> 4; int c4 = lin & 15;
        float4 v = make_float4(0.f,0.f,0.f,0.f);
        if (row < PN) v = *reinterpret_cast<const float4*>(Qb + (size_t)row * DIM + kbase + c4 * 4);
        ushort4 h; h.x=f2bf(v.x); h.y=f2bf(v.y); h.z=f2bf(v.z); h.w=f2bf(v.w);
        *reinterpret_cast<ushort4*>(&Qst[row][c4*4]) = h;
      }
      #pragma unroll
      for (int i = 0; i < 4; ++i) {
        int lin = i * 256 + tid; int row = lin >> 4; int c4 = lin & 15;
        int srow = sbase + row;
        float4 v = make_float4(0.f,0.f,0.f,0.f);
        if (srow < SSZ) v = *reinterpret_cast<const float4*>(Sb + (size_t)srow * DIM + kbase + c4 * 4);
        ushort4 h; h.x=f2bf(v.x); h.y=f2bf(v.y); h.z=f2bf(v.z); h.w=f2bf(v.w);
        *reinterpret_cast<ushort4*>(&Sst[row][c4*4]) = h;
      }
      __syncthreads();
      #pragma unroll
      for (int kk = 0; kk < 2; ++kk) {
        bf16x8 a0 = __builtin_bit_cast(bf16x8, *reinterpret_cast<const short8*>(&Qst[wv*32+ 0+l15][kk*32+quad*8]));
        bf16x8 a1 = __builtin_bit_cast(bf16x8, *reinterpret_cast<const short8*>(&Qst[wv*32+16+l15][kk*32+quad*8]));
        #pragma unroll
        for (int nt = 0; nt < 4; ++nt) {
          bf16x8 bb = __builtin_bit_cast(bf16x8, *reinterpret_cast<const short8*>(&Sst[nt*16+l15][kk*32+quad*8]));
          acc[0][nt] = __builtin_amdgcn_mfma_f32_16x16x32_bf16(a0, bb, acc[0][nt], 0,0,0);
          acc[1][nt] = __builtin_amdgcn_mfma_f32_16x16x32_bf16(a1, bb, acc[1][nt], 0,0,0);
        }
      }
    }
    #pragma unroll
    for (int mt = 0; mt < 2; ++mt)
      #pragma unroll
      for (int nt = 0; nt < 4; ++nt)
        #pragma unroll
        for (int r = 0; r < 4; ++r)
          Cs[wv*32+mt*16+quad*4+r][nt*16+l15] = acc[mt][nt][r];
    __syncthreads();
    {
      int row = tid >> 1; int half = tid & 1;
      float a = -3.0e38f, b2 = -3.0e38f, c = -3.0e38f;
      int c0 = half * 32; int cend = c0 + 32; if (cend > vn) cend = vn;
      for (int cc = c0; cc < cend; ++cc) ins3(a, b2, c, Cs[row][cc]);
      float o0 = __shfl_xor(a,1), o1 = __shfl_xor(b2,1), o2 = __shfl_xor(c,1);
      ins3(a,b2,c,o0); ins3(a,b2,c,o1); ins3(a,b2,c,o2);
      if (half == 0) {
        float r0=top3[row][0], r1=top3[row][1], r2=top3[row][2];
        ins3(r0,r1,r2,a); ins3(r0,r1,r2,b2); ins3(r0,r1,r2,c);
        top3[row][0]=r0; top3[row][1]=r1; top3[row][2]=r2;
      }
    }
    __syncthreads();
  }
  float s = 0.f;
  for (int i = tid; i < PN * TOPK; i += 256) s += top3[i/TOPK][i%TOPK];
  #pragma unroll
  for (int off = 32; off > 0; off >>= 1) s += __shfl_down(s, off);
  if (lane == 0) red[wv] = s;
  __syncthreads();
  if (tid == 0) out[bid] = (red[0]+red[1]+red[2]+red[3]) * (1.0f/(PN*TOPK));
}

// ---------------- launch ----------------
extern "C" void kernel_launch(void* const* d_in, const int* in_sizes, int n_in,
                              void* d_out, int out_size, void* d_ws, size_t ws_size,
                              hipStream_t stream) {
  const float* qf = (const float*)d_in[0];
  const float* sf = (const float*)d_in[1];
  float* out = (float*)d_out;
  (void)in_sizes; (void)n_in; (void)out_size;

  if (ws_size >= WS_NEED && d_ws != nullptr) {
    uint4* wq  = (uint4*)d_ws;
    uint4* wsp = wq + (size_t)NQTILES * 1024;

    // occupancy query once (pure host query — graph-capture safe)
    static int occ = -2;
    if (occ == -2) {
      int n = 0;
      if (hipOccupancyMaxActiveBlocksPerMultiprocessor(&n, lpc_fused, 256, 0)
          != hipSuccess) n = 0;
      occ = n;
    }

    bool done = false;
    if (occ >= 1) {
      int bpc  = occ > 3 ? 3 : occ;
      int nblk = bpc * 256;                  // 256 CUs; nblk % 8 == 0
      void* kargs[] = { (void*)&qf, (void*)&sf, (void*)&wq, (void*)&wsp,
                        (void*)&out, (void*)&nblk };
      if (hipLaunchCooperativeKernel((const void*)lpc_fused, dim3(nblk),
                                     dim3(256), kargs, 0, stream) == hipSuccess)
        done = true;
    }
    if (!done) {   // proven 2-kernel path
      cvt_pack<<<1600, 256, 0, stream>>>(qf, sf, wq, wsp);
      lpc_main<<<BATCH * NQ * WAY, 256, 0, stream>>>((const char*)wq, (const char*)wsp, out);
    }
  } else {
    lpc_fallback<<<BATCH * NQ * WAY, 256, 0, stream>>>(qf, sf, out);
  }
}

// Round 5
// 711.850 us; speedup vs baseline: 1.5414x; 1.5414x over previous
//
#include <hip/hip_runtime.h>
#include <hip/hip_bf16.h>

// Problem constants:
#define BATCH 8
#define NQ    75
#define WAY   5
#define PN    121
#define DIM   640
#define SSZ   605        // shot * patch_num
#define TOPK  3

#define KCH 10           // DIM / 64
#define NCH 5            // 640 / 128

// Workspace: bf16, MFMA-tile-packed, XOR-swizzled (chunk_phys = chunk_log ^ (row&7)).
//   Q: [bq=600][kc=10] tiles of [row=128][chunk=8]x16B  (6000 tiles)
//   S: [bw=40][nc=5][kc=10] tiles                        (2000 tiles)
#define NQTILES 6000
#define NSTILES 2000
#define WS_NEED   ((size_t)(NQTILES + NSTILES) * 16384)   // 131,072,000 B

typedef __attribute__((ext_vector_type(8))) short   short8;
typedef __attribute__((ext_vector_type(8))) __bf16  bf16x8;
typedef __attribute__((ext_vector_type(4))) float   f32x4;

__device__ inline unsigned short f2bf(float f) {
  unsigned u = __builtin_bit_cast(unsigned, f);
  return (unsigned short)((u + 0x7fffu + ((u >> 16) & 1u)) >> 16);
}
__device__ inline unsigned pk2(float lo, float hi) {
  return (unsigned)f2bf(lo) | ((unsigned)f2bf(hi) << 16);
}

// branchless insert into sorted-descending triple: 1 max + 2 med3
__device__ inline void ins3(float &a, float &b, float &c, float v) {
  float na  = fmaxf(a, v);
  float nb  = __builtin_amdgcn_fmed3f(v, a, b);
  float nc2 = __builtin_amdgcn_fmed3f(v, b, c);
  a = na; b = nb; c = nc2;
}

// async 16B global->LDS (DMA; LDS dest = wave-uniform base + lane*16)
__device__ inline void async_copy16(const void* g, void* l) {
  __builtin_amdgcn_global_load_lds(
      (const __attribute__((address_space(1))) unsigned int*)g,
      (__attribute__((address_space(3))) unsigned int*)l, 16, 0, 0);
}

// ---------------- pack unit: one 32-row quarter of one tile frame ------------
// Math HW-verified in round 4 (fused kernel used this and passed).
__device__ __forceinline__ void pack_unit(int unit_b, int j,
                                          const float* __restrict__ qf,
                                          const float* __restrict__ sf,
                                          uint4* __restrict__ wq,
                                          uint4* __restrict__ wsp) {
  const float* src;      // frame base (row 0 of the 128-row tile frame)
  uint4* dstbase;        // first kc tile of this frame
  int nrows, rowbase;
  if (j < 300) {
    const int q = j >> 2;
    rowbase = (j & 3) << 5;
    const int slab = unit_b * NQ + q;
    src = qf + (size_t)slab * PN * DIM;
    dstbase = wq + (size_t)slab * KCH * 1024;
    nrows = PN;
  } else {
    const int l = j - 300;
    rowbase = (l & 3) << 5;
    const int fi = l >> 2;          // 0..24 = w*5 + nc
    const int nc = fi % NCH;
    const int w  = fi / NCH;
    const int bw = unit_b * WAY + w;
    const int uv = bw * NCH + nc;
    src = sf + ((size_t)bw * SSZ + nc * 128) * DIM;
    dstbase = wsp + (size_t)uv * KCH * 1024;
    nrows = SSZ - nc * 128; if (nrows > 128) nrows = 128;
  }
  // 32 rows x 80 segments (8 floats in, 16B out each) = 2560 segs, 10 iters.
  #pragma unroll 2
  for (int i = 0; i < 10; ++i) {
    const int L    = i * 256 + threadIdx.x;   // 0..2559
    const int rowl = L / 80;
    const int s    = L - rowl * 80;           // 0..79: global 8-float segment
    const int row  = rowbase + rowl;          // tile-local row 0..127
    const int kc   = s >> 3;
    const int c    = s & 7;                   // logical chunk within kc window
    const int p    = c ^ (row & 7);           // physical chunk slot (swizzle)
    uint4 o = make_uint4(0u, 0u, 0u, 0u);
    if (row < nrows) {
      const float* g = src + (size_t)row * DIM + s * 8;
      float4 v0 = reinterpret_cast<const float4*>(g)[0];
      float4 v1 = reinterpret_cast<const float4*>(g)[1];
      o.x = pk2(v0.x, v0.y); o.y = pk2(v0.z, v0.w);
      o.z = pk2(v1.x, v1.y); o.w = pk2(v1.z, v1.w);
    }
    dstbase[(size_t)kc * 1024 + row * 8 + p] = o;
  }
}

// ---------------- pack kernel (standalone; ~60-90us, near its 60us roofline)
__global__ __launch_bounds__(256) void cvt_pack(const float* __restrict__ qf,
                                                const float* __restrict__ sf,
                                                uint4* __restrict__ wq,
                                                uint4* __restrict__ wsp) {
  const int blk = blockIdx.x;
  int b, j0;
  if (blk < 1200) { const int slab = blk >> 1; b = slab / NQ;
    j0 = (slab - b * NQ) * 4 + (blk & 1) * 2; }
  else { const int u = blk - 1200; const int uv = u >> 1;   // bw*5+nc
    const int bw = uv / NCH; b = bw / WAY;
    const int fi = (bw - b * WAY) * NCH + (uv % NCH);
    j0 = 300 + fi * 4 + (u & 1) * 2; }
  pack_unit(b, j0, qf, sf, wq, wsp);
  pack_unit(b, j0 + 1, qf, sf, wq, wsp);
}

// ---------------- main kernel v2: 256x128 tile, 8 waves, issue-early dbuf ----
// Round-4 attribution: lpc_main is ~83% of bench time; cvt_pack is near its
// roofline. This version raises the 904-TF 2-barrier ceiling by:
//  * BM=256 = TWO packed 128-row Q frames (workspace format unchanged),
//    BN=128: B staged once per q-PAIR (staged bytes 4.8 -> 3.65 GB), S tiles
//    re-read by 38 blocks per (b,w) instead of 75.
//  * catalog minimum-2-phase: STAGE(t+1) issued at TOP of step t into
//    buf[cur^1]; ONE __syncthreads() per step at the END. Its implicit
//    vmcnt(0) drain retires a DMA that has had the whole ds_read+32-MFMA
//    phase (~300+ cyc) to fly — the drain is harmless by construction.
//    (Round-1 failure kept the per-step pre-compute barrier; this doesn't.)
//  * 512 thr / 8 waves (4M x 2N of the proven 64x64 quadrant — acc, t3,
//    swizzle, fold, butterfly all verbatim). LDS 96KB dbuf -> 1 block/CU,
//    8 waves/CU (m201-class occupancy; pipeline replaces inter-block TLP).
// Grid 1520 = 8 batches x 190 (38 q-pairs x 5 w); sbid&7 = XCD-local batch.
// qp=37 pairs q=74 with invalid q=75: rows 128..255 stage in-bounds junk
// (worst case b=7 reads S-region bytes, finite bf16), output write guarded.
__global__ __launch_bounds__(512, 2) void lpc_main(
    const char* __restrict__ wq,    // packed Q tiles
    const char* __restrict__ wsp,   // packed S tiles
    float* __restrict__ out)        // [B, NQ, WAY]
{
  __shared__ char As[2][32768];     // 256 rows x 64 K bf16 (two 128-row frames)
  __shared__ char Bs[2][16384];     // 128 S-cols x 64 K bf16
  __shared__ float red[8];

  const int sbid = blockIdx.x;
  const int b    = sbid & 7;            // 1520 % 8 == 0: XCD k owns batch k
  const int bid2 = sbid >> 3;           // 0..189
  const int w    = bid2 % WAY;
  const int qp   = bid2 / WAY;          // 0..37  (consecutive 5 blocks share qp)
  const int q0   = qp * 2;

  const char* Qt0 = wq + (size_t)(b * NQ + q0) * KCH * 16384;
  const char* Qt1 = Qt0 + (size_t)KCH * 16384;  // frame of q0+1 (in-bounds junk if q0+1==75)
  const char* St  = wsp + (size_t)(b * WAY + w) * NCH * KCH * 16384;

  const int tid  = threadIdx.x;
  const int lane = tid & 63;
  const int wv   = tid >> 6;            // 0..7
  const int l15  = lane & 15;
  const int quad = lane >> 4;
  const int mrow0 = (wv >> 1) * 64;     // 0,64,128,192
  const int ncol0 = (wv & 1) * 64;      // 0,64

  // swizzled chunk byte offsets (XOR distributes over the <<4); row&7 is
  // frame-consistent since frame offset 128 == 0 mod 8.
  const int sw16 = (l15 & 7) * 16;
  const int cp0  = (quad * 16) ^ sw16;        // kk = 0
  const int cp1  = ((4 + quad) * 16) ^ sw16;  // kk = 1

  // staging: 48 x 1KB chunks/step (A frame0: 0..15, A frame1: 16..31, B: 32..47)
  // wave wv owns chunks [wv*6, wv*6+6) -> 6 async DMAs per wave per step.
  auto stage = [&](int buf, int tt, int kcc) {
    const char* a0 = Qt0 + (size_t)kcc * 16384;
    const char* a1 = Qt1 + (size_t)kcc * 16384;
    const char* bb = St  + (size_t)tt  * 16384;
    #pragma unroll
    for (int i = 0; i < 6; ++i) {
      const int c = wv * 6 + i;
      const char* src = (c < 16) ? a0 + c * 1024
                      : (c < 32) ? a1 + (c - 16) * 1024
                                 : bb + (c - 32) * 1024;
      char* dst = (c < 32) ? &As[buf][0] + c * 1024
                           : &Bs[buf][0] + (c - 32) * 1024;
      async_copy16(src + lane * 16, dst);
    }
  };

  // per-lane running top-3 for 16 owned rows: row = mrow0 + mt*16 + quad*4 + r
  float t3a[4][4], t3b[4][4], t3c[4][4];
  #pragma unroll
  for (int mt = 0; mt < 4; ++mt)
    #pragma unroll
    for (int r = 0; r < 4; ++r) {
      t3a[mt][r] = -3.0e38f; t3b[mt][r] = -3.0e38f; t3c[mt][r] = -3.0e38f;
    }

  // prologue: stage step 0 into buf0; the implicit vmcnt(0) in __syncthreads
  // completes it.
  stage(0, 0, 0);
  __syncthreads();

  f32x4 acc[4][4];
  int cur = 0, kc = 0, nc = 0;

  // 50 flattened K-steps; S tile index == t (S slab linear in (nc,kc)).
  #pragma unroll 1
  for (int t = 0; t < NCH * KCH; ++t) {
    if (kc == 0) {
      #pragma unroll
      for (int mt = 0; mt < 4; ++mt)
        #pragma unroll
        for (int nt = 0; nt < 4; ++nt)
          acc[mt][nt] = (f32x4){0.f, 0.f, 0.f, 0.f};
    }

    // issue-early: next step's DMA flies under this step's compute
    if (t < NCH * KCH - 1) {
      const int kc2 = (kc == 9) ? 0 : kc + 1;
      stage(cur ^ 1, t + 1, kc2);
    }

    const char* qb = &As[cur][0] + (mrow0 + l15) * 128;
    const char* sb = &Bs[cur][0] + (ncol0 + l15) * 128;
    #pragma unroll
    for (int kk = 0; kk < 2; ++kk) {
      const int cp = kk ? cp1 : cp0;
      short8 a[4], bf[4];
      #pragma unroll
      for (int mt = 0; mt < 4; ++mt)
        a[mt] = *reinterpret_cast<const short8*>(qb + mt * 2048 + cp);
      #pragma unroll
      for (int nt = 0; nt < 4; ++nt)
        bf[nt] = *reinterpret_cast<const short8*>(sb + nt * 2048 + cp);
      #pragma unroll
      for (int mt = 0; mt < 4; ++mt)
        #pragma unroll
        for (int nt = 0; nt < 4; ++nt)
          acc[mt][nt] = __builtin_amdgcn_mfma_f32_16x16x32_bf16(
              __builtin_bit_cast(bf16x8, a[mt]),
              __builtin_bit_cast(bf16x8, bf[nt]), acc[mt][nt], 0, 0, 0);
    }

    if (kc == 9) {
      // fold this 128-col chunk into register top-3 (mask pad cols >= 605);
      // register-only, overlaps the in-flight DMA.
      #pragma unroll
      for (int nt = 0; nt < 4; ++nt) {
        const int col = nc * 128 + ncol0 + nt * 16 + l15;
        const bool valid = col < SSZ;
        #pragma unroll
        for (int mt = 0; mt < 4; ++mt)
          #pragma unroll
          for (int r = 0; r < 4; ++r) {
            float v = valid ? acc[mt][nt][r] : -3.0e38f;
            ins3(t3a[mt][r], t3b[mt][r], t3c[mt][r], v);
          }
      }
      kc = 0; ++nc;
    } else {
      ++kc;
    }

    // ONE barrier per step. Implicit vmcnt(0) drains stage(t+1) (covered by
    // the compute above); implicit lgkmcnt(0) retires this step's ds_reads
    // before buf[cur] is overwritten next step.
    __syncthreads();
    cur ^= 1;
  }

  // butterfly-merge top-3 across the 16 l15 lanes (same rows, different cols)
  #pragma unroll
  for (int m = 1; m < 16; m <<= 1) {
    #pragma unroll
    for (int mt = 0; mt < 4; ++mt)
      #pragma unroll
      for (int r = 0; r < 4; ++r) {
        float o0 = __shfl_xor(t3a[mt][r], m);
        float o1 = __shfl_xor(t3b[mt][r], m);
        float o2 = __shfl_xor(t3c[mt][r], m);
        ins3(t3a[mt][r], t3b[mt][r], t3c[mt][r], o0);
        ins3(t3a[mt][r], t3b[mt][r], t3c[mt][r], o1);
        ins3(t3a[mt][r], t3b[mt][r], t3c[mt][r], o2);
      }
  }

  // cross-N-wave merge via LDS scratch (reuse As): odd waves publish; even
  // waves (same mrow0) merge and republish. tb[256][3] = 3KB.
  float* tb = reinterpret_cast<float*>(As);
  __syncthreads();
  if ((wv & 1) == 1 && l15 == 0) {
    #pragma unroll
    for (int mt = 0; mt < 4; ++mt)
      #pragma unroll
      for (int r = 0; r < 4; ++r) {
        int row = mrow0 + mt * 16 + quad * 4 + r;
        tb[row * 3 + 0] = t3a[mt][r];
        tb[row * 3 + 1] = t3b[mt][r];
        tb[row * 3 + 2] = t3c[mt][r];
      }
  }
  __syncthreads();
  if ((wv & 1) == 0 && l15 == 0) {
    #pragma unroll
    for (int mt = 0; mt < 4; ++mt)
      #pragma unroll
      for (int r = 0; r < 4; ++r) {
        int row = mrow0 + mt * 16 + quad * 4 + r;
        ins3(t3a[mt][r], t3b[mt][r], t3c[mt][r], tb[row * 3 + 0]);
        ins3(t3a[mt][r], t3b[mt][r], t3c[mt][r], tb[row * 3 + 1]);
        ins3(t3a[mt][r], t3b[mt][r], t3c[mt][r], tb[row * 3 + 2]);
      }
  }
  __syncthreads();
  if ((wv & 1) == 0 && l15 == 0) {
    #pragma unroll
    for (int mt = 0; mt < 4; ++mt)
      #pragma unroll
      for (int r = 0; r < 4; ++r) {
        int row = mrow0 + mt * 16 + quad * 4 + r;
        tb[row * 3 + 0] = t3a[mt][r];
        tb[row * 3 + 1] = t3b[mt][r];
        tb[row * 3 + 2] = t3c[mt][r];
      }
  }
  __syncthreads();

  // mean over valid rows and k: rows 0..120 -> q0 (waves 0-3),
  // rows 128..248 -> q0+1 (waves 4-7; float base 128*3=384).
  const int half = tid >> 8;
  float s = 0.f;
  for (int j = tid & 255; j < PN * TOPK; j += 256) s += tb[half * 384 + j];
  #pragma unroll
  for (int off = 32; off > 0; off >>= 1) s += __shfl_down(s, off);
  if (lane == 0) red[wv] = s;
  __syncthreads();
  if (tid == 0)
    out[(size_t)(b * NQ + q0) * WAY + w] =
        (red[0] + red[1] + red[2] + red[3]) * (1.0f / (PN * TOPK));
  if (tid == 256 && q0 + 1 < NQ)
    out[(size_t)(b * NQ + q0 + 1) * WAY + w] =
        (red[4] + red[5] + red[6] + red[7]) * (1.0f / (PN * TOPK));
}

// ---------------- fallback (direct from fp32, only if ws too small) ---------
__global__ __launch_bounds__(256) void lpc_fallback(
    const float* __restrict__ qf, const float* __restrict__ sf,
    float* __restrict__ out)
{
  __shared__ short Qst[128][72];
  __shared__ short Sst[64][72];
  __shared__ float Cs[128][67];
  __shared__ float top3[128][TOPK];
  __shared__ float red[4];

  const int bid = blockIdx.x;
  const int w   = bid % WAY;
  const int qi  = (bid / WAY) % NQ;
  const int b   = bid / (WAY * NQ);
  const float* Qb = qf + ((size_t)(b * NQ + qi)) * PN * DIM;
  const float* Sb = sf + ((size_t)(b * WAY + w)) * SSZ * DIM;
  const int tid  = threadIdx.x;
  const int lane = tid & 63;
  const int wv   = tid >> 6;
  const int l15  = lane & 15;
  const int quad = lane >> 4;

  if (tid < 128) { top3[tid][0] = -3.0e38f; top3[tid][1] = -3.0e38f; top3[tid][2] = -3.0e38f; }
  f32x4 acc[2][4];
  for (int nc = 0; nc < 10; ++nc) {
    const int sbase = nc * 64;
    int vn = SSZ - sbase; if (vn > 64) vn = 64;
    #pragma unroll
    for (int mt = 0; mt < 2; ++mt)
      #pragma unroll
      for (int nt = 0; nt < 4; ++nt) acc[mt][nt] = (f32x4){0.f,0.f,0.f,0.f};
    for (int kc = 0; kc < KCH; ++kc) {
      const int kbase = kc * 64;
      __syncthreads();
      #pragma unroll
      for (int i = 0; i < 8; ++i) {
        int lin = i * 256 + tid; int row = lin >> 4; int c4 = lin & 15;
        float4 v = make_float4(0.f,0.f,0.f,0.f);
        if (row < PN) v = *reinterpret_cast<const float4*>(Qb + (size_t)row * DIM + kbase + c4 * 4);
        ushort4 h; h.x=f2bf(v.x); h.y=f2bf(v.y); h.z=f2bf(v.z); h.w=f2bf(v.w);
        *reinterpret_cast<ushort4*>(&Qst[row][c4*4]) = h;
      }
      #pragma unroll
      for (int i = 0; i < 4; ++i) {
        int lin = i * 256 + tid; int row = lin >> 4; int c4 = lin & 15;
        int srow = sbase + row;
        float4 v = make_float4(0.f,0.f,0.f,0.f);
        if (srow < SSZ) v = *reinterpret_cast<const float4*>(Sb + (size_t)srow * DIM + kbase + c4 * 4);
        ushort4 h; h.x=f2bf(v.x); h.y=f2bf(v.y); h.z=f2bf(v.z); h.w=f2bf(v.w);
        *reinterpret_cast<ushort4*>(&Sst[row][c4*4]) = h;
      }
      __syncthreads();
      #pragma unroll
      for (int kk = 0; kk < 2; ++kk) {
        bf16x8 a0 = __builtin_bit_cast(bf16x8, *reinterpret_cast<const short8*>(&Qst[wv*32+ 0+l15][kk*32+quad*8]));
        bf16x8 a1 = __builtin_bit_cast(bf16x8, *reinterpret_cast<const short8*>(&Qst[wv*32+16+l15][kk*32+quad*8]));
        #pragma unroll
        for (int nt = 0; nt < 4; ++nt) {
          bf16x8 bb = __builtin_bit_cast(bf16x8, *reinterpret_cast<const short8*>(&Sst[nt*16+l15][kk*32+quad*8]));
          acc[0][nt] = __builtin_amdgcn_mfma_f32_16x16x32_bf16(a0, bb, acc[0][nt], 0,0,0);
          acc[1][nt] = __builtin_amdgcn_mfma_f32_16x16x32_bf16(a1, bb, acc[1][nt], 0,0,0);
        }
      }
    }
    #pragma unroll
    for (int mt = 0; mt < 2; ++mt)
      #pragma unroll
      for (int nt = 0; nt < 4; ++nt)
        #pragma unroll
        for (int r = 0; r < 4; ++r)
          Cs[wv*32+mt*16+quad*4+r][nt*16+l15] = acc[mt][nt][r];
    __syncthreads();
    {
      int row = tid >> 1; int half = tid & 1;
      float a = -3.0e38f, b2 = -3.0e38f, c = -3.0e38f;
      int c0 = half * 32; int cend = c0 + 32; if (cend > vn) cend = vn;
      for (int cc = c0; cc < cend; ++cc) ins3(a, b2, c, Cs[row][cc]);
      float o0 = __shfl_xor(a,1), o1 = __shfl_xor(b2,1), o2 = __shfl_xor(c,1);
      ins3(a,b2,c,o0); ins3(a,b2,c,o1); ins3(a,b2,c,o2);
      if (half == 0) {
        float r0=top3[row][0], r1=top3[row][1], r2=top3[row][2];
        ins3(r0,r1,r2,a); ins3(r0,r1,r2,b2); ins3(r0,r1,r2,c);
        top3[row][0]=r0; top3[row][1]=r1; top3[row][2]=r2;
      }
    }
    __syncthreads();
  }
  float s = 0.f;
  for (int i = tid; i < PN * TOPK; i += 256) s += top3[i/TOPK][i%TOPK];
  #pragma unroll
  for (int off = 32; off > 0; off >>= 1) s += __shfl_down(s, off);
  if (lane == 0) red[wv] = s;
  __syncthreads();
  if (tid == 0) out[bid] = (red[0]+red[1]+red[2]+red[3]) * (1.0f/(PN*TOPK));
}

// ---------------- launch ----------------
extern "C" void kernel_launch(void* const* d_in, const int* in_sizes, int n_in,
                              void* d_out, int out_size, void* d_ws, size_t ws_size,
                              hipStream_t stream) {
  const float* qf = (const float*)d_in[0];
  const float* sf = (const float*)d_in[1];
  float* out = (float*)d_out;
  (void)in_sizes; (void)n_in; (void)out_size;

  if (ws_size >= WS_NEED && d_ws != nullptr) {
    uint4* wq  = (uint4*)d_ws;
    uint4* wsp = wq + (size_t)NQTILES * 1024;
    cvt_pack<<<1600, 256, 0, stream>>>(qf, sf, wq, wsp);
    lpc_main<<<BATCH * NQ * WAY / 2 + BATCH * WAY / 2, 512, 0, stream>>>(  // 1520
        (const char*)wq, (const char*)wsp, out);
  } else {
    lpc_fallback<<<BATCH * NQ * WAY, 256, 0, stream>>>(qf, sf, out);
  }
}